// Round 1
// baseline (612.426 us; speedup 1.0000x reference)
//
#include <hip/hip_runtime.h>
#include <math.h>

#define NOBS  192
#define MTEST 64
#define NF    256
#define KP    32
#define DD    8
#define NK    (NF*KP)              /* 8192 */
#define NPAIR ((NF*(NF+1))/2)      /* 32896 */
#define NRHS  66                   /* 64 Kox cols + (ys-b) + ones */

#define ROF(i) ((((i)*((i)+1))>>1))

/* ws layout (float offsets) */
#define WS_Z   0
#define WS_A   (WS_Z + NK*DD)         /* 65536 */
#define WS_C   (WS_A + NK)            /* 73728 */
#define WS_KOO (WS_C + NF*NF)         /* 139264 */
#define WS_KOX (WS_KOO + NOBS*NOBS)   /* 176128 */
#define WS_KXX (WS_KOX + NOBS*MTEST)  /* 188416; end = 192512 floats = 770KB */

// K0: Z = Xcat / rho_base (exact div once), Acat = concat(A_obs, A_test)
__global__ __launch_bounds__(256) void k0_prep(
    const float* __restrict__ Xo, const float* __restrict__ Ao,
    const float* __restrict__ Xt, const float* __restrict__ At,
    const float* __restrict__ rho_base, float* __restrict__ Z, float* __restrict__ Acat) {
  int idx = blockIdx.x * 256 + threadIdx.x;
  if (idx < NK * DD) {
    int t = idx & (DD - 1);
    float x = (idx < NOBS * KP * DD) ? Xo[idx] : Xt[idx - NOBS * KP * DD];
    Z[idx] = x / rho_base[t];
  } else {
    int a = idx - NK * DD;
    if (a < NK)
      Acat[a] = (a < NOBS * KP) ? Ao[a] : At[a - NOBS * KP];
  }
}

// K1: one wave per function-pair (i<=j):
//   C[i,j] = sum_{p,q} A[i,p] A[j,q] exp(-0.5*||z_ip - z_jq||^2)
__global__ __launch_bounds__(256) void k1_C(
    const float* __restrict__ Z, const float* __restrict__ A, float* __restrict__ C) {
  int wid = blockIdx.x * 4 + (threadIdx.x >> 6);
  if (wid >= NPAIR) return;
  int t = wid;
  // decode triangular index: base(i) = i*(513-i)/2, largest i with base(i) <= t
  double disc = 513.0 * 513.0 - 8.0 * (double)t;
  int i = (int)((513.0 - sqrt(disc)) * 0.5);
  if (i < 0) i = 0;
  if (i > 255) i = 255;
  while (i > 0 && (i * (513 - i)) / 2 > t) --i;
  while (i < 255 && ((i + 1) * (513 - (i + 1))) / 2 <= t) ++i;
  int j = i + (t - (i * (513 - i)) / 2);

  int lane = threadIdx.x & 63;
  int lq = lane & 31;       // q index
  int half = lane >> 5;     // p-half
  const float4* Zq = (const float4*)(Z + (j * KP + lq) * DD);
  float4 zq0 = Zq[0], zq1 = Zq[1];
  float aj = A[j * KP + lq];
  float acc = 0.f;
#pragma unroll
  for (int p16 = 0; p16 < 16; ++p16) {
    int p = half * 16 + p16;
    const float4* Zp = (const float4*)(Z + (i * KP + p) * DD);
    float4 zp0 = Zp[0], zp1 = Zp[1];
    float d, d2 = 0.f;
    d = zp0.x - zq0.x; d2 = fmaf(d, d, d2);
    d = zp0.y - zq0.y; d2 = fmaf(d, d, d2);
    d = zp0.z - zq0.z; d2 = fmaf(d, d, d2);
    d = zp0.w - zq0.w; d2 = fmaf(d, d, d2);
    d = zp1.x - zq1.x; d2 = fmaf(d, d, d2);
    d = zp1.y - zq1.y; d2 = fmaf(d, d, d2);
    d = zp1.z - zq1.z; d2 = fmaf(d, d, d2);
    d = zp1.w - zq1.w; d2 = fmaf(d, d, d2);
    float ai = A[i * KP + p];
    acc = fmaf(ai, expf(-0.5f * d2), acc);
  }
  acc *= aj;
#pragma unroll
  for (int off = 32; off > 0; off >>= 1) acc += __shfl_xor(acc, off, 64);
  if (lane == 0) {
    C[i * NF + j] = acc;
    C[j * NF + i] = acc;
  }
}

// K2: Kf(i,j) = exp(-0.5*max(C_ii+C_jj-2C_ij,0)/rho) * nu, packed into Koo/Kox/Kxx
__global__ __launch_bounds__(256) void k2_kf(
    const float* __restrict__ C, float* __restrict__ Koo, float* __restrict__ Kox,
    float* __restrict__ Kxx, const float* __restrict__ prho,
    const float* __restrict__ pg, const float* __restrict__ pnu) {
  int e = blockIdx.x * 256 + threadIdx.x;
  int i = e >> 8, j = e & 255;
  float Cii = C[i * NF + i], Cjj = C[j * NF + j], Cij = C[e];
  float D2 = Cii + Cjj - 2.f * Cij;
  D2 = D2 > 0.f ? D2 : 0.f;
  float nu = pnu[0];
  float kf = expf((-0.5f * D2) / prho[0]) * nu;
  if (i < NOBS) {
    if (j < NOBS)
      Koo[i * NOBS + j] = kf + (i == j ? nu * pg[0] : 0.f);
    else
      Kox[i * MTEST + (j - NOBS)] = kf;
  } else if (j >= NOBS) {
    Kxx[(i - NOBS) * MTEST + (j - NOBS)] = kf;
  }
}

// K3: single workgroup. LDL^T of Koo (packed lower, LDS) + 66-RHS solves + GP outputs.
//   B = [Kox | ys-b | ones];  G = Koo^-1 Kox, u = Koo^-1(ys-b), w = Koo^-1 1
//   mean = b + Kox^T u;  cov = Kxx - Kox^T G + (1-Kox^T w)(1-Kox^T w)^T / sum(w)
__global__ __launch_bounds__(1024) void k3_solve(
    const float* __restrict__ Koo, const float* __restrict__ Kox,
    const float* __restrict__ Kxx, const float* __restrict__ ys,
    const float* __restrict__ pb, float* __restrict__ out) {
  __shared__ float Lp[ROF(192)];        // 18528 floats = 74.1 KB
  __shared__ float Bm[NOBS * NRHS];     // 12672 floats = 50.7 KB
  __shared__ float invd[NOBS];
  __shared__ float kbxm[MTEST];
  __shared__ float sden;
  int tid = threadIdx.x;
  float bscal = pb[0];

  // load packed lower triangle of Koo
  for (int p = tid; p < ROF(192); p += 1024) {
    int i = (int)((sqrt(8.0 * p + 1.0) - 1.0) * 0.5);
    if (i < 0) i = 0;
    if (i > 191) i = 191;
    while (i < 191 && ROF(i + 1) <= p) ++i;
    while (i > 0 && ROF(i) > p) --i;
    int j = p - ROF(i);
    Lp[p] = Koo[i * NOBS + j];
  }
  // load RHS bundle
  for (int e = tid; e < NOBS * NRHS; e += 1024) {
    int i = e / NRHS, c = e - i * NRHS;
    float v;
    if (c < MTEST) v = Kox[i * MTEST + c];
    else if (c == MTEST) v = ys[i] - bscal;
    else v = 1.0f;
    Bm[e] = v;
  }
  __syncthreads();

  // in-place LDL^T (unscaled columns; one barrier per step)
  int tx = tid & 31, ty = tid >> 5;
  for (int k = 0; k < NOBS; ++k) {
    float id = 1.0f / Lp[ROF(k) + k];
    for (int ii = k + 1 + ty; ii < NOBS; ii += 32) {
      int roi = ROF(ii);
      float f = Lp[roi + k] * id;
      for (int jj = k + 1 + tx; jj <= ii; jj += 32) {
        Lp[roi + jj] -= f * Lp[ROF(jj) + k];
      }
    }
    __syncthreads();
  }
  if (tid < NOBS) invd[tid] = 1.0f / Lp[ROF(tid) + tid];
  __syncthreads();

  // forward solve, unit L (L[i][k] = A[i][k]*invd[k])
  int tc = tid % NRHS;
  int tr = tid / NRHS;
  bool act = (tid < 15 * NRHS);
  for (int k = 0; k < NOBS - 1; ++k) {
    if (act) {
      float yk = Bm[k * NRHS + tc] * invd[k];
      for (int i = k + 1 + tr; i < NOBS; i += 15) {
        Bm[i * NRHS + tc] -= Lp[ROF(i) + k] * yk;
      }
    }
    __syncthreads();
  }
  // scale by D^-1
  for (int e = tid; e < NOBS * NRHS; e += 1024) {
    int i = e / NRHS;
    Bm[e] *= invd[i];
  }
  __syncthreads();
  // backward solve, unit L^T (L[k][i] = A[k][i]*invd[i])
  for (int k = NOBS - 1; k > 0; --k) {
    if (act) {
      float xk = Bm[k * NRHS + tc];
      int rok = ROF(k);
      for (int i = tr; i < k; i += 15) {
        Bm[i * NRHS + tc] -= Lp[rok + i] * invd[i] * xk;
      }
    }
    __syncthreads();
  }

  // outputs
  if (tid < MTEST) {
    int j = tid;
    float mv = 0.f, kbx = 0.f;
    for (int i = 0; i < NOBS; ++i) {
      float kox = Kox[i * MTEST + j];
      mv = fmaf(kox, Bm[i * NRHS + 64], mv);
      kbx = fmaf(kox, Bm[i * NRHS + 65], kbx);
    }
    out[j] = bscal + mv;
    kbxm[j] = 1.0f - kbx;
  } else if (tid == MTEST) {
    float s = 0.f;
    for (int i = 0; i < NOBS; ++i) s += Bm[i * NRHS + 65];
    sden = 1.0f / s;
  }
  __syncthreads();
  for (int e = tid; e < MTEST * MTEST; e += 1024) {
    int a = e >> 6, bb = e & 63;
    float s = Kxx[e];
    for (int i = 0; i < NOBS; ++i)
      s = fmaf(-Kox[i * MTEST + a], Bm[i * NRHS + bb], s);
    s = fmaf(kbxm[a] * kbxm[bb], sden, s);
    out[MTEST + e] = s;
  }
}

extern "C" void kernel_launch(void* const* d_in, const int* in_sizes, int n_in,
                              void* d_out, int out_size, void* d_ws, size_t ws_size,
                              hipStream_t stream) {
  const float* Xo = (const float*)d_in[0];
  const float* Ao = (const float*)d_in[1];
  const float* Xt = (const float*)d_in[2];
  const float* At = (const float*)d_in[3];
  const float* ys = (const float*)d_in[4];
  const float* rb = (const float*)d_in[5];
  const float* prho = (const float*)d_in[6];
  const float* pg = (const float*)d_in[7];
  const float* pnu = (const float*)d_in[8];
  const float* pb = (const float*)d_in[9];
  float* ws = (float*)d_ws;
  float* Z = ws + WS_Z;
  float* Acat = ws + WS_A;
  float* C = ws + WS_C;
  float* Koo = ws + WS_KOO;
  float* Kox = ws + WS_KOX;
  float* Kxx = ws + WS_KXX;
  float* out = (float*)d_out;

  hipLaunchKernelGGL(k0_prep, dim3((NK * DD + NK + 255) / 256), dim3(256), 0, stream,
                     Xo, Ao, Xt, At, rb, Z, Acat);
  hipLaunchKernelGGL(k1_C, dim3((NPAIR + 3) / 4), dim3(256), 0, stream, Z, Acat, C);
  hipLaunchKernelGGL(k2_kf, dim3(NF * NF / 256), dim3(256), 0, stream,
                     C, Koo, Kox, Kxx, prho, pg, pnu);
  hipLaunchKernelGGL(k3_solve, dim3(1), dim3(1024), 0, stream, Koo, Kox, Kxx, ys, pb, out);
}

// Round 2
// 318.010 us; speedup vs baseline: 1.9258x; 1.9258x over previous
//
#include <hip/hip_runtime.h>
#include <math.h>

#define NOBS  192
#define MTEST 64
#define NF    256
#define KP    32
#define DD    8
#define NK    (NF*KP)              /* 8192 */
#define NPAIR ((NF*(NF+1))/2)      /* 32896 */
#define NB    32                   /* Cholesky block */
#define NBLK  6
#define NCOL  68                   /* padded RHS cols: 64 Kox + ys + ones + 2 pad */

/* padded packed-lower-triangle offset: rows padded to multiple of 4 floats so
   every row is 16B-aligned for ds_read_b128. PROF(192)=18816 floats. */
__device__ __host__ __forceinline__ int PROF(int i) {
  int a = i >> 2, m = i & 3;
  return ((a + 1) * ((a << 1) + m)) << 2;
}

/* ws layout (float offsets) */
#define WS_Z   0                      /* 65536 */
#define WS_A   (WS_Z + NK*DD)         /* 8192  */
#define WS_MH  (WS_A + NK)            /* 8192  */
#define WS_C   (WS_MH + NK)           /* 65536 (reused as S after k2 done) */
#define WS_KOO (WS_C + NF*NF)         /* 36864 */
#define WS_KOX (WS_KOO + NOBS*NOBS)   /* 12288 */
#define WS_KXX (WS_KOX + NOBS*MTEST)  /* 4096  */
#define WS_S   WS_C                   /* 192*68 = 13056, overwrites C */

// K0: per support point: z' = (x / rho_base) * sqrt(log2 e); mh = -0.5*||z'||^2
__global__ __launch_bounds__(256) void k0_prep(
    const float* __restrict__ Xo, const float* __restrict__ Ao,
    const float* __restrict__ Xt, const float* __restrict__ At,
    const float* __restrict__ rho_base, float* __restrict__ Z,
    float* __restrict__ Acat, float* __restrict__ MH) {
  int p = blockIdx.x * 256 + threadIdx.x;
  if (p >= NK) return;
  const float* xp = (p < NOBS * KP) ? (Xo + p * DD) : (Xt + (p - NOBS * KP) * DD);
  float4 x0 = *(const float4*)(xp);
  float4 x1 = *(const float4*)(xp + 4);
  float4 r0 = *(const float4*)(rho_base);
  float4 r1 = *(const float4*)(rho_base + 4);
  const float s = 1.2011224087864498f;  // sqrt(log2(e))
  float z0 = x0.x / r0.x * s, z1 = x0.y / r0.y * s, z2 = x0.z / r0.z * s, z3 = x0.w / r0.w * s;
  float z4 = x1.x / r1.x * s, z5 = x1.y / r1.y * s, z6 = x1.z / r1.z * s, z7 = x1.w / r1.w * s;
  float n = z0 * z0 + z1 * z1 + z2 * z2 + z3 * z3 + z4 * z4 + z5 * z5 + z6 * z6 + z7 * z7;
  *(float4*)(Z + p * DD) = make_float4(z0, z1, z2, z3);
  *(float4*)(Z + p * DD + 4) = make_float4(z4, z5, z6, z7);
  MH[p] = -0.5f * n;
  Acat[p] = (p < NOBS * KP) ? Ao[p] : At[p - NOBS * KP];
}

// K1: one wave per function-pair (i<=j):
//   C[i,j] = sum_{p,q} A[i,p] A[j,q] exp2(zp.zq + mh_p + mh_q)   (z pre-scaled)
__global__ __launch_bounds__(256) void k1_C(
    const float* __restrict__ Z, const float* __restrict__ A,
    const float* __restrict__ MH, float* __restrict__ C) {
  int wid = blockIdx.x * 4 + (threadIdx.x >> 6);
  if (wid >= NPAIR) return;
  int t = wid;
  double disc = 513.0 * 513.0 - 8.0 * (double)t;
  int i = (int)((513.0 - sqrt(disc)) * 0.5);
  if (i < 0) i = 0;
  if (i > 255) i = 255;
  while (i > 0 && (i * (513 - i)) / 2 > t) --i;
  while (i < 255 && ((i + 1) * (513 - (i + 1))) / 2 <= t) ++i;
  int j = i + (t - (i * (513 - i)) / 2);

  int lane = threadIdx.x & 63;
  int lq = lane & 31;
  int half = lane >> 5;
  const float4* Zq = (const float4*)(Z + (j * KP + lq) * DD);
  float4 zq0 = Zq[0], zq1 = Zq[1];
  float aj = A[j * KP + lq];
  float mq = MH[j * KP + lq];
  float acc = 0.f;
#pragma unroll
  for (int p16 = 0; p16 < 16; ++p16) {
    int ip = i * KP + half * 16 + p16;
    const float4* Zp = (const float4*)(Z + ip * DD);
    float4 zp0 = Zp[0], zp1 = Zp[1];
    float d = zp0.x * zq0.x;
    d = fmaf(zp0.y, zq0.y, d);
    d = fmaf(zp0.z, zq0.z, d);
    d = fmaf(zp0.w, zq0.w, d);
    d = fmaf(zp1.x, zq1.x, d);
    d = fmaf(zp1.y, zq1.y, d);
    d = fmaf(zp1.z, zq1.z, d);
    d = fmaf(zp1.w, zq1.w, d);
    float arg = d + MH[ip] + mq;
    float ex;
    asm("v_exp_f32 %0, %1" : "=v"(ex) : "v"(arg));  // 2^arg
    acc = fmaf(A[ip], ex, acc);
  }
  acc *= aj;
#pragma unroll
  for (int off = 32; off > 0; off >>= 1) acc += __shfl_xor(acc, off, 64);
  if (lane == 0) {
    C[i * NF + j] = acc;
    C[j * NF + i] = acc;
  }
}

// K2: Kf(i,j) = nu * exp(-0.5*max(Cii+Cjj-2Cij,0)/rho), packed into Koo/Kox/Kxx
__global__ __launch_bounds__(256) void k2_kf(
    const float* __restrict__ C, float* __restrict__ Koo, float* __restrict__ Kox,
    float* __restrict__ Kxx, const float* __restrict__ prho,
    const float* __restrict__ pg, const float* __restrict__ pnu) {
  int e = blockIdx.x * 256 + threadIdx.x;
  int i = e >> 8, j = e & 255;
  float Cii = C[i * NF + i], Cjj = C[j * NF + j], Cij = C[e];
  float D2 = Cii + Cjj - 2.f * Cij;
  D2 = D2 > 0.f ? D2 : 0.f;
  float nu = pnu[0];
  float kf = expf((-0.5f * D2) / prho[0]) * nu;
  if (i < NOBS) {
    if (j < NOBS)
      Koo[i * NOBS + j] = kf + (i == j ? nu * pg[0] : 0.f);
    else
      Kox[i * MTEST + (j - NOBS)] = kf;
  } else if (j >= NOBS) {
    Kxx[(i - NOBS) * MTEST + (j - NOBS)] = kf;
  }
}

// K3: blocked Cholesky (NB=32) of Koo, diag blocks factored+inverted in-register
// by wave 0; forward solve ONLY for S = L^-1 [Kox | ys-b | 1]; S -> ws.
__global__ __launch_bounds__(512) void k3_factor_solve(
    const float* __restrict__ Koo, const float* __restrict__ Kox,
    const float* __restrict__ ys, const float* __restrict__ pb,
    float* __restrict__ Sout) {
  __shared__ float Lp[18816];        // padded packed lower triangle, 75264 B
  __shared__ float Bm[NOBS * NCOL];  // RHS bundle, 52224 B
  __shared__ float Pn[160 * 34];     // current L21 panel, padded stride 34, 21760 B
  __shared__ float Mi[32 * 36];      // scratch: L11 rows, then inv(L11) rows

  int tid = threadIdx.x;
  int lane = tid & 63;
  int w = tid >> 6;
  float bs = pb[0];

  // ---- load Koo lower triangle + RHS bundle ----
  for (int i = w; i < NOBS; i += 8) {
    int base = PROF(i);
    for (int l = lane; l <= i; l += 64) Lp[base + l] = Koo[i * NOBS + l];
  }
  for (int i = w; i < NOBS; i += 8) {
    for (int l = lane; l < NCOL; l += 64) {
      float v;
      if (l < 64) v = Kox[i * MTEST + l];
      else if (l == 64) v = ys[i] - bs;
      else if (l == 65) v = 1.0f;
      else v = 0.0f;
      Bm[i * NCOL + l] = v;
    }
  }
  __syncthreads();

  // ---- factorization: for each block: diag factor+invert, panel, trailing ----
  for (int b = 0; b < NBLK; ++b) {
    int kb = b * NB;
    int rem = NOBS - kb - NB;

    // Phase A (wave 0, lanes 0..31): Cholesky of 32x32 diag block in registers,
    // then triangular inverse; inv(L11) overwrites diag block in Lp and fills Mi.
    if (w == 0 && lane < 32) {
      float row[32];
      int base = PROF(kb + lane) + kb;
#pragma unroll
      for (int c = 0; c < 32; c += 4) {
        float4 v = *(const float4*)&Lp[base + c];
        row[c] = v.x; row[c + 1] = v.y; row[c + 2] = v.z; row[c + 3] = v.w;
      }
      // right-looking Cholesky; lane l owns row l (cols <= l valid)
#pragma unroll
      for (int j = 0; j < 32; ++j) {
        float dj = __shfl(row[j], j, 64);
        float rs = 1.0f / sqrtf(dj);
        float cl = row[j] * rs;
        row[j] = cl;
#pragma unroll
        for (int c = j + 1; c < 32; ++c)
          row[c] = fmaf(-cl, __shfl(cl, c, 64), row[c]);
      }
      // stash L rows to Mi for column-wise access
#pragma unroll
      for (int c = 0; c < 32; c += 4) {
        *(float4*)&Mi[lane * 36 + c] =
            make_float4(row[c], row[c + 1], row[c + 2], row[c + 3]);
      }
      // invert: lane c computes column c of M = inv(L); zeros above diag emerge
      float x[32];
#pragma unroll
      for (int i2 = 0; i2 < 32; ++i2) {
        float vi = Mi[i2 * 36 + lane];  // lane k holds L[i2][k]
        float acc = (i2 == lane) ? 1.0f : 0.0f;
#pragma unroll
        for (int k = 0; k < 32; ++k) {
          if (k < i2) acc = fmaf(-__shfl(vi, k, 64), x[k], acc);
        }
        float Lii = __shfl(vi, i2, 64);
        x[i2] = acc / Lii;
      }
      // Mi row i := M[i][*] (lane c writes col c); also overwrite Lp diag block
#pragma unroll
      for (int i2 = 0; i2 < 32; ++i2) Mi[i2 * 36 + lane] = x[i2];
#pragma unroll
      for (int i2 = 0; i2 < 32; ++i2)
        if (lane <= i2) Lp[PROF(kb + i2) + kb + lane] = x[i2];
    }
    __syncthreads();

    if (rem > 0) {
      // Phase B: panel L21 = A21 * M^T  (M = inv(L11), rows in Mi, zero-padded)
      int c = tid & 31;
      int rb = tid >> 5;  // 0..15
      float Mreg[32];
#pragma unroll
      for (int q = 0; q < 32; q += 4) {
        float4 v = *(const float4*)&Mi[c * 36 + q];
        Mreg[q] = v.x; Mreg[q + 1] = v.y; Mreg[q + 2] = v.z; Mreg[q + 3] = v.w;
      }
      float outv[10];
#pragma unroll 10
      for (int rr = 0; rr < 10; ++rr) {
        int r = rb + rr * 16;
        float res = 0.f;
        if (r < rem) {
          int abase = PROF(kb + NB + r) + kb;
          float a0 = 0.f, a1 = 0.f, a2 = 0.f, a3 = 0.f;
#pragma unroll
          for (int q = 0; q < 32; q += 4) {
            float4 av = *(const float4*)&Lp[abase + q];
            a0 = fmaf(av.x, Mreg[q], a0);
            a1 = fmaf(av.y, Mreg[q + 1], a1);
            a2 = fmaf(av.z, Mreg[q + 2], a2);
            a3 = fmaf(av.w, Mreg[q + 3], a3);
          }
          res = (a0 + a1) + (a2 + a3);
        }
        outv[rr] = res;
      }
      __syncthreads();
#pragma unroll 10
      for (int rr = 0; rr < 10; ++rr) {
        int r = rb + rr * 16;
        if (r < rem) {
          Lp[PROF(kb + NB + r) + kb + c] = outv[rr];
          Pn[r * 34 + c] = outv[rr];
        }
      }
    }
    __syncthreads();

    if (rem > 0) {
      // Phase C: trailing update A22 -= L21 L21^T (lower triangle only).
      // Wave covers 64 cols (lane-owned panel rows cached in regs), rows strided.
      for (int c0 = 0; c0 < rem; c0 += 64) {
        int cc = c0 + lane;
        float Pc[32];
#pragma unroll
        for (int q = 0; q < 32; q += 2) {
          float2 v = *(const float2*)&Pn[cc * 34 + q];  // cc<160 always in-bounds
          Pc[q] = v.x; Pc[q + 1] = v.y;
        }
        for (int r = c0 + w; r < rem; r += 8) {
          float a0 = 0.f, a1 = 0.f, a2 = 0.f, a3 = 0.f;
#pragma unroll
          for (int q = 0; q < 32; q += 8) {
            float2 u0 = *(const float2*)&Pn[r * 34 + q];
            float2 u1 = *(const float2*)&Pn[r * 34 + q + 2];
            float2 u2 = *(const float2*)&Pn[r * 34 + q + 4];
            float2 u3 = *(const float2*)&Pn[r * 34 + q + 6];
            a0 = fmaf(u0.x, Pc[q], a0);     a1 = fmaf(u0.y, Pc[q + 1], a1);
            a2 = fmaf(u1.x, Pc[q + 2], a2); a3 = fmaf(u1.y, Pc[q + 3], a3);
            a0 = fmaf(u2.x, Pc[q + 4], a0); a1 = fmaf(u2.y, Pc[q + 5], a1);
            a2 = fmaf(u3.x, Pc[q + 6], a2); a3 = fmaf(u3.y, Pc[q + 7], a3);
          }
          float tot = (a0 + a1) + (a2 + a3);
          if (cc <= r) {
            int idx = PROF(kb + NB + r) + kb + NB + cc;
            Lp[idx] -= tot;
          }
        }
      }
    }
    __syncthreads();
  }

  // ---- forward solve: B <- L^-1 B, block by block ----
  for (int b = 0; b < NBLK; ++b) {
    int kb = b * NB;
    int rem = NOBS - kb - NB;
    // D1: Y_b = inv(L11_b) * B_b   (inv stored in Lp diag block, upper = stale -> mask)
    {
      int c = tid >> 4;      // 0..31
      int colb = tid & 15;
      float Mreg[32];
      int mbase = PROF(kb + c) + kb;
#pragma unroll
      for (int q = 0; q < 32; q += 4) {
        float4 v = *(const float4*)&Lp[mbase + q];
        Mreg[q] = v.x; Mreg[q + 1] = v.y; Mreg[q + 2] = v.z; Mreg[q + 3] = v.w;
      }
#pragma unroll
      for (int q = 0; q < 32; ++q)
        if (q > c) Mreg[q] = 0.f;
      float outs[5];
#pragma unroll 5
      for (int jj = 0; jj < 5; ++jj) {
        int col = colb + 16 * jj;
        float a0 = 0.f, a1 = 0.f, a2 = 0.f, a3 = 0.f;
        if (col < NCOL) {
#pragma unroll
          for (int k = 0; k < 32; k += 4) {
            a0 = fmaf(Mreg[k],     Bm[(kb + k) * NCOL + col], a0);
            a1 = fmaf(Mreg[k + 1], Bm[(kb + k + 1) * NCOL + col], a1);
            a2 = fmaf(Mreg[k + 2], Bm[(kb + k + 2) * NCOL + col], a2);
            a3 = fmaf(Mreg[k + 3], Bm[(kb + k + 3) * NCOL + col], a3);
          }
        }
        outs[jj] = (a0 + a1) + (a2 + a3);
      }
      __syncthreads();
#pragma unroll 5
      for (int jj = 0; jj < 5; ++jj) {
        int col = colb + 16 * jj;
        if (col < NCOL) Bm[(kb + c) * NCOL + col] = outs[jj];
      }
      __syncthreads();
    }
    // D2: B_below -= L21 * Y_b ; lane owns RHS column (Y cached in regs)
    if (rem > 0) {
      float y[32], y2[32];
      bool has2 = lane < 4;
      int col2 = 64 + lane;
#pragma unroll
      for (int k = 0; k < 32; ++k) {
        y[k] = Bm[(kb + k) * NCOL + lane];
        y2[k] = has2 ? Bm[(kb + k) * NCOL + col2] : 0.f;
      }
      for (int r = w; r < rem; r += 8) {
        int rowg = kb + NB + r;
        int lbase = PROF(rowg) + kb;
        float a0 = Bm[rowg * NCOL + lane], a1 = 0.f;
        float b0 = has2 ? Bm[rowg * NCOL + col2] : 0.f, b1 = 0.f;
#pragma unroll
        for (int q = 0; q < 32; q += 4) {
          float4 lv = *(const float4*)&Lp[lbase + q];
          a0 = fmaf(-lv.x, y[q], a0);     b0 = fmaf(-lv.x, y2[q], b0);
          a1 = fmaf(-lv.y, y[q + 1], a1); b1 = fmaf(-lv.y, y2[q + 1], b1);
          a0 = fmaf(-lv.z, y[q + 2], a0); b0 = fmaf(-lv.z, y2[q + 2], b0);
          a1 = fmaf(-lv.w, y[q + 3], a1); b1 = fmaf(-lv.w, y2[q + 3], b1);
        }
        Bm[rowg * NCOL + lane] = a0 + a1;
        if (has2) Bm[rowg * NCOL + col2] = b0 + b1;
      }
    }
    __syncthreads();
  }

  // ---- dump S = L^-1 [Kox | ys-b | 1 | pad] ----
  for (int e = tid; e < NOBS * NCOL; e += 512) Sout[e] = Bm[e];
}

// K4: epilogue across 64 blocks: mean, cov from S (stride NCOL).
//   cov = Kxx - S_x^T S_x + (1 - S_x^T s1)(...)^T / (s1.s1); mean = b + S_x^T s_y
__global__ __launch_bounds__(64) void k4_post(
    const float* __restrict__ S, const float* __restrict__ Kxx,
    const float* __restrict__ pb, float* __restrict__ out) {
  int a = blockIdx.x;
  int bb = threadIdx.x;
  float cv0 = 0.f, cv1 = 0.f, m0 = 0.f, m1 = 0.f;
  float ka0 = 0.f, ka1 = 0.f, kc0 = 0.f, kc1 = 0.f, d0 = 0.f, d1 = 0.f;
#pragma unroll 4
  for (int i = 0; i < NOBS; i += 2) {
    float sa0 = S[i * NCOL + a],        sb0 = S[i * NCOL + bb];
    float sy0 = S[i * NCOL + 64],       s10 = S[i * NCOL + 65];
    float sa1 = S[(i + 1) * NCOL + a],  sb1 = S[(i + 1) * NCOL + bb];
    float sy1 = S[(i + 1) * NCOL + 64], s11 = S[(i + 1) * NCOL + 65];
    cv0 = fmaf(sa0, sb0, cv0);  cv1 = fmaf(sa1, sb1, cv1);
    m0 = fmaf(sa0, sy0, m0);    m1 = fmaf(sa1, sy1, m1);
    ka0 = fmaf(sa0, s10, ka0);  ka1 = fmaf(sa1, s11, ka1);
    kc0 = fmaf(sb0, s10, kc0);  kc1 = fmaf(sb1, s11, kc1);
    d0 = fmaf(s10, s10, d0);    d1 = fmaf(s11, s11, d1);
  }
  float kbxa = 1.f - (ka0 + ka1);
  float kbxb = 1.f - (kc0 + kc1);
  float den = d0 + d1;
  out[MTEST + a * MTEST + bb] = Kxx[a * MTEST + bb] - (cv0 + cv1) + kbxa * kbxb / den;
  if (bb == 0) out[a] = pb[0] + (m0 + m1);
}

extern "C" void kernel_launch(void* const* d_in, const int* in_sizes, int n_in,
                              void* d_out, int out_size, void* d_ws, size_t ws_size,
                              hipStream_t stream) {
  const float* Xo = (const float*)d_in[0];
  const float* Ao = (const float*)d_in[1];
  const float* Xt = (const float*)d_in[2];
  const float* At = (const float*)d_in[3];
  const float* ys = (const float*)d_in[4];
  const float* rb = (const float*)d_in[5];
  const float* prho = (const float*)d_in[6];
  const float* pg = (const float*)d_in[7];
  const float* pnu = (const float*)d_in[8];
  const float* pb = (const float*)d_in[9];
  float* ws = (float*)d_ws;
  float* Z = ws + WS_Z;
  float* Acat = ws + WS_A;
  float* MH = ws + WS_MH;
  float* C = ws + WS_C;
  float* Koo = ws + WS_KOO;
  float* Kox = ws + WS_KOX;
  float* Kxx = ws + WS_KXX;
  float* S = ws + WS_S;
  float* out = (float*)d_out;

  hipLaunchKernelGGL(k0_prep, dim3(NK / 256), dim3(256), 0, stream,
                     Xo, Ao, Xt, At, rb, Z, Acat, MH);
  hipLaunchKernelGGL(k1_C, dim3((NPAIR + 3) / 4), dim3(256), 0, stream, Z, Acat, MH, C);
  hipLaunchKernelGGL(k2_kf, dim3(NF * NF / 256), dim3(256), 0, stream,
                     C, Koo, Kox, Kxx, prho, pg, pnu);
  hipLaunchKernelGGL(k3_factor_solve, dim3(1), dim3(512), 0, stream, Koo, Kox, ys, pb, S);
  hipLaunchKernelGGL(k4_post, dim3(MTEST), dim3(MTEST), 0, stream, S, Kxx, pb, out);
}